// Round 7
// baseline (481.491 us; speedup 1.0000x reference)
//
#include <hip/hip_runtime.h>
#include <math.h>

#define DD 64
#define BROWS 256         // rows per bucket (bucket = row >> 8)
#define CHUNK 8192        // edges per kbin block (16 per thread, 512 threads)
constexpr float FEPS = 1e-15f;
constexpr float MAXN = 1.0f - 4e-3f;   // Poincare-ball projection radius (c=1)

__device__ __forceinline__ float wsum(float v) {
    v += __shfl_xor(v, 32);
    v += __shfl_xor(v, 16);
    v += __shfl_xor(v, 8);
    v += __shfl_xor(v, 4);
    v += __shfl_xor(v, 2);
    v += __shfl_xor(v, 1);
    return v;
}

__device__ __forceinline__ float artanh_c(float x) {
    x = fminf(fmaxf(x, -1.f + 1e-7f), 1.f - 1e-7f);
    return 0.5f * logf((1.f + x) / (1.f - x));
}

// hbuf[0..63] = proj(expmap0(b)), hbuf[64] = |hbuf|^2
__global__ void khb_kernel(const float* __restrict__ b, float* __restrict__ hbuf) {
    int lane = threadIdx.x;
    float bv = b[lane];
    float n2 = wsum(bv * bv);
    float n = fmaxf(sqrtf(n2), FEPS);
    float th = tanhf(n);
    float p = th * (bv / n);
    float pn = th * (sqrtf(n2) / n);
    float pn_c = fmaxf(pn, FEPS);
    if (pn_c > MAXN) p *= MAXN / pn_c;
    float p2 = wsum(p * p);
    hbuf[lane] = p;
    if (lane == 0) hbuf[DD] = p2;
}

// 512 threads = 8 waves per 64-node tile; wave w owns rows [8w,8w+8).
// x tile staged coalesced into LDS (pitch 65); W on the scalar s_load path.
__global__ __launch_bounds__(512) void klinear(
    const float* __restrict__ x, const float* __restrict__ W,
    const float* __restrict__ hbuf, float* __restrict__ xt, int n_nodes) {
    __shared__ float tile[DD * 65];
    __shared__ float red0[8][DD];
    __shared__ float red1[8][DD];
    const int t = threadIdx.x;
    const int lane = t & 63;
    const int w = t >> 6;
    const int n0 = blockIdx.x * DD;

    #pragma unroll
    for (int rep = 0; rep < 2; ++rep) {
        int i = rep * 512 + t;
        int nd = i >> 4, q = i & 15;
        int node = n0 + nd;
        const float4* src = reinterpret_cast<const float4*>(
            x + (size_t)(node < n_nodes ? node : 0) * DD);
        float4 v = src[q];
        float* d = &tile[nd * 65 + q * 4];
        d[0] = v.x; d[1] = v.y; d[2] = v.z; d[3] = v.w;
    }
    __syncthreads();

    const int jbase = __builtin_amdgcn_readfirstlane(w) * 8;
    float mx[8] = {0.f, 0.f, 0.f, 0.f, 0.f, 0.f, 0.f, 0.f};
    float xn2 = 0.f;
    #pragma unroll
    for (int kk = 0; kk < 4; ++kk) {
        float xv[16];
        #pragma unroll
        for (int ki = 0; ki < 16; ++ki)
            xv[ki] = tile[lane * 65 + kk * 16 + ki];
        #pragma unroll
        for (int ki = 0; ki < 16; ++ki)
            xn2 = fmaf(xv[ki], xv[ki], xn2);
        #pragma unroll
        for (int jj = 0; jj < 8; ++jj) {
            const float* Wr = W + (jbase + jj) * DD + kk * 16;   // uniform -> s_load
            float a = mx[jj];
            #pragma unroll
            for (int ki = 0; ki < 16; ++ki) a = fmaf(Wr[ki], xv[ki], a);
            mx[jj] = a;
        }
    }
    float mx2p = 0.f, mxhp = 0.f;
    #pragma unroll
    for (int jj = 0; jj < 8; ++jj) {
        mx2p = fmaf(mx[jj], mx[jj], mx2p);
        mxhp = fmaf(mx[jj], hbuf[jbase + jj], mxhp);
    }
    red0[w][lane] = mx2p;
    red1[w][lane] = mxhp;
    __syncthreads();
    float mx2 = 0.f, mxh = 0.f;
    #pragma unroll
    for (int ww = 0; ww < 8; ++ww) {     // identical order -> bitwise-equal in all waves
        mx2 += red0[ww][lane];
        mxh += red1[ww][lane];
    }

    float xn = fmaxf(sqrtf(xn2), FEPS);
    float mxn = fmaxf(sqrtf(mx2), FEPS);
    float th = tanhf((mxn / xn) * artanh_c(xn));
    float sres = (mx2 == 0.f) ? 0.f : th / mxn;
    float rn = (mx2 == 0.f) ? 0.f : th * (sqrtf(mx2) / mxn);
    float rn_c = fmaxf(rn, FEPS);
    float s1 = (rn_c > MAXN) ? sres * (MAXN / rn_c) : sres;
    float x2r = s1 * s1 * mx2;
    float xy = s1 * mxh;
    float y2 = hbuf[DD];
    float ca = 1.f + 2.f * xy + y2;
    float cb = 1.f - x2r;
    float rden = 1.f / fmaxf(1.f + 2.f * xy + x2r * y2, FEPS);
    float al = ca * s1 * rden;
    float be = cb * rden;
    float h2 = al * al * mx2 + 2.f * al * be * mxh + be * be * y2;
    float hn = fmaxf(sqrtf(h2), FEPS);
    float sh = 1.f;
    if (hn > MAXN) { sh = MAXN / hn; hn = MAXN; }
    float su = sh * (artanh_c(hn) / hn);
    float A = su * al, B = su * be;

    #pragma unroll
    for (int jj = 0; jj < 8; ++jj)
        tile[lane * 65 + jbase + jj] = fmaf(A, mx[jj], B * hbuf[jbase + jj]);
    __syncthreads();

    float4* dst = reinterpret_cast<float4*>(xt + (size_t)n0 * DD);
    #pragma unroll
    for (int rep = 0; rep < 2; ++rep) {
        int i = rep * 512 + t;
        int nd = i >> 4, q = i & 15;
        if (n0 + nd < n_nodes) {
            const float* s = &tile[nd * 65 + q * 4];
            dst[i] = make_float4(s[0], s[1], s[2], s[3]);
        }
    }
}

// counting-sort binning: block-private contiguous ranges per bucket
// -> dense writes, ~38k global atomics instead of 800k.
__global__ __launch_bounds__(512) void kbin(
    const int* __restrict__ erow, const int* __restrict__ ecol,
    const float* __restrict__ eval_, int* __restrict__ gcnt,
    int4* __restrict__ binned, int cap, int n_edges) {
    __shared__ int lcnt[512];
    __shared__ int goff[512];
    const int t = threadIdx.x;
    const int eb = blockIdx.x * CHUNK;
    lcnt[t] = 0;
    __syncthreads();
    int rk[16];
    #pragma unroll
    for (int i = 0; i < 16; ++i) {
        int e = eb + i * 512 + t;
        rk[i] = -1;
        if (e < n_edges) {
            int bkt = erow[e] >> 8;                 // bucket of 256 rows
            int r = atomicAdd(&lcnt[bkt], 1);       // local rank (LDS)
            rk[i] = (bkt << 13) | r;                // r < 8192 fits 13 bits
        }
    }
    __syncthreads();
    {
        int c = lcnt[t];
        if (c > 0) goff[t] = atomicAdd(&gcnt[t], c);   // reserve range
    }
    __syncthreads();
    #pragma unroll
    for (int i = 0; i < 16; ++i) {
        int e = eb + i * 512 + t;
        if (e >= n_edges) continue;
        int bkt = rk[i] >> 13, r = rk[i] & 8191;
        int pos = goff[bkt] + r;
        if (pos < cap)
            binned[(size_t)bkt * cap + pos] =
                make_int4(erow[e], ecol[e], __float_as_int(eval_[e]), 0);
    }
}

// folded epilogue: o = K(n2, sp2) * relu(s)
__device__ __forceinline__ void agg_epilogue(
    float4 acc, int row, int fl, float* __restrict__ out) {
    float4 s;
    s.x = fminf(acc.x, 1e6f); s.y = fminf(acc.y, 1e6f);
    s.z = fminf(acc.z, 1e6f); s.w = fminf(acc.w, 1e6f);
    float4 rs;
    rs.x = fmaxf(s.x, 0.f); rs.y = fmaxf(s.y, 0.f);
    rs.z = fmaxf(s.z, 0.f); rs.w = fmaxf(s.w, 0.f);
    float n2p = s.x * s.x + s.y * s.y + s.z * s.z + s.w * s.w;
    float sp2p = rs.x * rs.x + rs.y * rs.y + rs.z * rs.z + rs.w * rs.w;
    #pragma unroll
    for (int m = 1; m < 16; m <<= 1) {
        n2p += __shfl_xor(n2p, m);
        sp2p += __shfl_xor(sp2p, m);
    }
    float n = fmaxf(sqrtf(n2p), FEPS);
    float th = tanhf(n);
    float c1 = th / n;
    float pn = th * (sqrtf(n2p) / n);
    float pn_c = fmaxf(pn, FEPS);
    if (pn_c > MAXN) { c1 *= MAXN / pn_c; pn_c = MAXN; }
    float k1 = (artanh_c(pn_c) / pn_c) * c1;
    float u2 = k1 * k1 * sp2p;
    float un = fmaxf(sqrtf(u2), FEPS);
    float t2 = tanhf(un);
    float k2 = (t2 / un) * k1;
    float on = t2 * (sqrtf(u2) / un);
    float on_c = fmaxf(on, FEPS);
    if (on_c > MAXN) k2 *= MAXN / on_c;
    float4 o;
    o.x = k2 * rs.x; o.y = k2 * rs.y; o.z = k2 * rs.z; o.w = k2 * rs.w;
    reinterpret_cast<float4*>(out)[(size_t)row * 16 + fl] = o;
}

// block per bucket: accumulate 256 rows x 64 feats in a 64 KB LDS accumulator
// via ds_add_f32, then fused epilogue + dense output write.
__global__ __launch_bounds__(512) void kaggb(
    const int* __restrict__ gcnt, const int4* __restrict__ binned, int cap,
    const float* __restrict__ xt, float* __restrict__ out, int n_nodes) {
    __shared__ float acc[BROWS * DD];    // 64 KB
    const int t = threadIdx.x;
    const int g = t >> 4;                // 16-lane group 0..31
    const int fl = t & 15;               // float4 slot within row
    const int b = blockIdx.x;
    for (int i = t; i < BROWS * DD; i += 512) acc[i] = 0.f;
    __syncthreads();
    int nrec = min(gcnt[b], cap);
    const int4* rec = binned + (size_t)b * cap;
    const float4* xtf4 = reinterpret_cast<const float4*>(xt);
    for (int j = g; j < nrec; j += 32) {
        int4 e = rec[j];                           // (row, col, w, 0)
        int lr = e.x & (BROWS - 1);
        float wv = __int_as_float(e.z);
        float4 v = xtf4[(size_t)e.y * 16 + fl];    // 16 lanes = 256B dense
        float* a = &acc[lr * DD + fl * 4];
        atomicAdd(a + 0, wv * v.x);                // ds_add_f32
        atomicAdd(a + 1, wv * v.y);
        atomicAdd(a + 2, wv * v.z);
        atomicAdd(a + 3, wv * v.w);
    }
    __syncthreads();
    #pragma unroll
    for (int it = 0; it < BROWS / 32; ++it) {
        int lr = it * 32 + g;
        int row = b * BROWS + lr;
        if (row < n_nodes) {
            const float* a = &acc[lr * DD + fl * 4];
            agg_epilogue(make_float4(a[0], a[1], a[2], a[3]), row, fl, out);
        }
    }
}

extern "C" void kernel_launch(void* const* d_in, const int* in_sizes, int n_in,
                              void* d_out, int out_size, void* d_ws, size_t ws_size,
                              hipStream_t stream) {
    const float* x     = (const float*)d_in[0];
    const float* W     = (const float*)d_in[1];
    const float* b     = (const float*)d_in[2];
    const int*   erow  = (const int*)d_in[3];
    const int*   ecol  = (const int*)d_in[4];
    const float* eval_ = (const float*)d_in[5];
    const int n_nodes = in_sizes[0] / DD;   // 100000
    const int n_edges = in_sizes[3];        // 800000
    float* out = (float*)d_out;

    const int NBKT = (n_nodes + BROWS - 1) / BROWS;     // 391

    // cap sized from ws: fixed tail = xt + hbuf + gcnt
    size_t fixed = (size_t)n_nodes * DD * 4 + 80 * 4 + 512 * 4;
    size_t avail = (ws_size > fixed) ? (ws_size - fixed) : 0;
    size_t caps = avail / ((size_t)NBKT * 16);
    int cap = (int)(caps > 4096 ? 4096 : caps);         // mean deg*256 ~ 2046; >40 sigma

    // ws layout: binned (16B-aligned at base) | xt | hbuf | gcnt
    int4*  binned = (int4*)d_ws;
    float* xt     = (float*)(binned + (size_t)NBKT * cap);
    float* hbuf   = xt + (size_t)n_nodes * DD;
    int*   gcnt   = (int*)(hbuf + 80);

    const int nbB = (n_edges + CHUNK - 1) / CHUNK;      // 98
    const int nbL = (n_nodes + DD - 1) / DD;

    hipMemsetAsync(gcnt, 0, 512 * sizeof(int), stream);
    khb_kernel<<<1, 64, 0, stream>>>(b, hbuf);
    kbin<<<nbB, 512, 0, stream>>>(erow, ecol, eval_, gcnt, binned, cap, n_edges);
    klinear<<<nbL, 512, 0, stream>>>(x, W, hbuf, xt, n_nodes);
    kaggb<<<NBKT, 512, 0, stream>>>(gcnt, binned, cap, xt, out, n_nodes);
}

// Round 8
// 161.399 us; speedup vs baseline: 2.9832x; 2.9832x over previous
//
#include <hip/hip_runtime.h>
#include <hip/hip_fp16.h>
#include <math.h>

#define DD 64
#define BK 128            // rows per bucket (bucket = row >> 7)
#define BCAP 2048         // records per bucket (mean ~1023; +32 sigma)
#define NBKT_MAX 800
#define CHUNK 8192        // edges per kbin block (16 per thread, 512 threads)
constexpr float FEPS = 1e-15f;
constexpr float MAXN = 1.0f - 4e-3f;   // Poincare-ball projection radius (c=1)

__device__ __forceinline__ float wsum(float v) {
    v += __shfl_xor(v, 32);
    v += __shfl_xor(v, 16);
    v += __shfl_xor(v, 8);
    v += __shfl_xor(v, 4);
    v += __shfl_xor(v, 2);
    v += __shfl_xor(v, 1);
    return v;
}

__device__ __forceinline__ int wave_incl_scan(int v) {
    int lane = threadIdx.x & 63;
    #pragma unroll
    for (int d = 1; d < 64; d <<= 1) {
        int t = __shfl_up(v, d);
        if (lane >= d) v += t;
    }
    return v;
}

__device__ __forceinline__ float artanh_c(float x) {
    x = fminf(fmaxf(x, -1.f + 1e-7f), 1.f - 1e-7f);
    return 0.5f * logf((1.f + x) / (1.f - x));
}

// hbuf[0..63] = proj(expmap0(b)), hbuf[64] = |hbuf|^2
__global__ void khb_kernel(const float* __restrict__ b, float* __restrict__ hbuf) {
    int lane = threadIdx.x;
    float bv = b[lane];
    float n2 = wsum(bv * bv);
    float n = fmaxf(sqrtf(n2), FEPS);
    float th = tanhf(n);
    float p = th * (bv / n);
    float pn = th * (sqrtf(n2) / n);
    float pn_c = fmaxf(pn, FEPS);
    if (pn_c > MAXN) p *= MAXN / pn_c;
    float p2 = wsum(p * p);
    hbuf[lane] = p;
    if (lane == 0) hbuf[DD] = p2;
}

// 512 threads = 8 waves per 64-node tile; W on the scalar s_load path.
// Output xt now stored as fp16 (halves agg gather footprint).
__global__ __launch_bounds__(512) void klinear(
    const float* __restrict__ x, const float* __restrict__ W,
    const float* __restrict__ hbuf, __half* __restrict__ xth, int n_nodes) {
    __shared__ float tile[DD * 65];
    __shared__ float red0[8][DD];
    __shared__ float red1[8][DD];
    const int t = threadIdx.x;
    const int lane = t & 63;
    const int w = t >> 6;
    const int n0 = blockIdx.x * DD;

    #pragma unroll
    for (int rep = 0; rep < 2; ++rep) {
        int i = rep * 512 + t;
        int nd = i >> 4, q = i & 15;
        int node = n0 + nd;
        const float4* src = reinterpret_cast<const float4*>(
            x + (size_t)(node < n_nodes ? node : 0) * DD);
        float4 v = src[q];
        float* d = &tile[nd * 65 + q * 4];
        d[0] = v.x; d[1] = v.y; d[2] = v.z; d[3] = v.w;
    }
    __syncthreads();

    const int jbase = __builtin_amdgcn_readfirstlane(w) * 8;
    float mx[8] = {0.f, 0.f, 0.f, 0.f, 0.f, 0.f, 0.f, 0.f};
    float xn2 = 0.f;
    #pragma unroll
    for (int kk = 0; kk < 4; ++kk) {
        float xv[16];
        #pragma unroll
        for (int ki = 0; ki < 16; ++ki)
            xv[ki] = tile[lane * 65 + kk * 16 + ki];
        #pragma unroll
        for (int ki = 0; ki < 16; ++ki)
            xn2 = fmaf(xv[ki], xv[ki], xn2);
        #pragma unroll
        for (int jj = 0; jj < 8; ++jj) {
            const float* Wr = W + (jbase + jj) * DD + kk * 16;   // uniform -> s_load
            float a = mx[jj];
            #pragma unroll
            for (int ki = 0; ki < 16; ++ki) a = fmaf(Wr[ki], xv[ki], a);
            mx[jj] = a;
        }
    }
    float mx2p = 0.f, mxhp = 0.f;
    #pragma unroll
    for (int jj = 0; jj < 8; ++jj) {
        mx2p = fmaf(mx[jj], mx[jj], mx2p);
        mxhp = fmaf(mx[jj], hbuf[jbase + jj], mxhp);
    }
    red0[w][lane] = mx2p;
    red1[w][lane] = mxhp;
    __syncthreads();
    float mx2 = 0.f, mxh = 0.f;
    #pragma unroll
    for (int ww = 0; ww < 8; ++ww) {     // identical order -> bitwise-equal in all waves
        mx2 += red0[ww][lane];
        mxh += red1[ww][lane];
    }

    float xn = fmaxf(sqrtf(xn2), FEPS);
    float mxn = fmaxf(sqrtf(mx2), FEPS);
    float th = tanhf((mxn / xn) * artanh_c(xn));
    float sres = (mx2 == 0.f) ? 0.f : th / mxn;
    float rn = (mx2 == 0.f) ? 0.f : th * (sqrtf(mx2) / mxn);
    float rn_c = fmaxf(rn, FEPS);
    float s1 = (rn_c > MAXN) ? sres * (MAXN / rn_c) : sres;
    float x2r = s1 * s1 * mx2;
    float xy = s1 * mxh;
    float y2 = hbuf[DD];
    float ca = 1.f + 2.f * xy + y2;
    float cb = 1.f - x2r;
    float rden = 1.f / fmaxf(1.f + 2.f * xy + x2r * y2, FEPS);
    float al = ca * s1 * rden;
    float be = cb * rden;
    float h2 = al * al * mx2 + 2.f * al * be * mxh + be * be * y2;
    float hn = fmaxf(sqrtf(h2), FEPS);
    float sh = 1.f;
    if (hn > MAXN) { sh = MAXN / hn; hn = MAXN; }
    float su = sh * (artanh_c(hn) / hn);
    float A = su * al, B = su * be;

    #pragma unroll
    for (int jj = 0; jj < 8; ++jj)
        tile[lane * 65 + jbase + jj] = fmaf(A, mx[jj], B * hbuf[jbase + jj]);
    __syncthreads();

    // coalesced fp16 store (8B per thread-item)
    uint2* dst = reinterpret_cast<uint2*>(xth + (size_t)n0 * DD);
    #pragma unroll
    for (int rep = 0; rep < 2; ++rep) {
        int i = rep * 512 + t;
        int nd = i >> 4, q = i & 15;
        if (n0 + nd < n_nodes) {
            const float* s = &tile[nd * 65 + q * 4];
            __half2 h0 = __floats2half2_rn(s[0], s[1]);
            __half2 h1 = __floats2half2_rn(s[2], s[3]);
            uint2 o;
            o.x = *reinterpret_cast<unsigned int*>(&h0);
            o.y = *reinterpret_cast<unsigned int*>(&h1);
            dst[i] = o;
        }
    }
}

// counting-sort binning into 128-row buckets; packed 8B records:
// x = (localrow << 17) | col, y = weight bits. Dense per-(block,bucket) runs.
__global__ __launch_bounds__(512) void kbin(
    const int* __restrict__ erow, const int* __restrict__ ecol,
    const float* __restrict__ eval_, int* __restrict__ gcnt,
    int2* __restrict__ binned, int nbkt, int n_edges) {
    __shared__ int lcnt[NBKT_MAX];
    __shared__ int goff[NBKT_MAX];
    const int t = threadIdx.x;
    const int eb = blockIdx.x * CHUNK;
    for (int i = t; i < nbkt; i += 512) lcnt[i] = 0;
    __syncthreads();
    int rk[16];
    int rowv[16];
    #pragma unroll
    for (int i = 0; i < 16; ++i) {
        int e = eb + i * 512 + t;
        rk[i] = -1;
        if (e < n_edges) {
            int r = erow[e];
            rowv[i] = r;
            int bkt = r >> 7;
            int rank = atomicAdd(&lcnt[bkt], 1);    // rank < 8192: 13 bits
            rk[i] = (bkt << 13) | rank;
        }
    }
    __syncthreads();
    for (int i = t; i < nbkt; i += 512) {
        int c = lcnt[i];
        if (c > 0) goff[i] = atomicAdd(&gcnt[i], c);   // reserve contiguous range
    }
    __syncthreads();
    #pragma unroll
    for (int i = 0; i < 16; ++i) {
        int e = eb + i * 512 + t;
        if (e >= n_edges) continue;
        int bkt = rk[i] >> 13, rank = rk[i] & 8191;
        int pos = goff[bkt] + rank;
        if (pos < BCAP) {
            int lr = rowv[i] & (BK - 1);
            binned[(size_t)bkt * BCAP + pos] =
                make_int2((lr << 17) | ecol[e], __float_as_int(eval_[e]));
        }
    }
}

// folded epilogue: o = K(n2, sp2) * relu(s)
__device__ __forceinline__ void agg_epilogue(
    float4 acc, int row, int fl, float* __restrict__ out) {
    float4 s;
    s.x = fminf(acc.x, 1e6f); s.y = fminf(acc.y, 1e6f);
    s.z = fminf(acc.z, 1e6f); s.w = fminf(acc.w, 1e6f);
    float4 rs;
    rs.x = fmaxf(s.x, 0.f); rs.y = fmaxf(s.y, 0.f);
    rs.z = fmaxf(s.z, 0.f); rs.w = fmaxf(s.w, 0.f);
    float n2p = s.x * s.x + s.y * s.y + s.z * s.z + s.w * s.w;
    float sp2p = rs.x * rs.x + rs.y * rs.y + rs.z * rs.z + rs.w * rs.w;
    #pragma unroll
    for (int m = 1; m < 16; m <<= 1) {
        n2p += __shfl_xor(n2p, m);
        sp2p += __shfl_xor(sp2p, m);
    }
    float n = fmaxf(sqrtf(n2p), FEPS);
    float th = tanhf(n);
    float c1 = th / n;
    float pn = th * (sqrtf(n2p) / n);
    float pn_c = fmaxf(pn, FEPS);
    if (pn_c > MAXN) { c1 *= MAXN / pn_c; pn_c = MAXN; }
    float k1 = (artanh_c(pn_c) / pn_c) * c1;
    float u2 = k1 * k1 * sp2p;
    float un = fmaxf(sqrtf(u2), FEPS);
    float t2 = tanhf(un);
    float k2 = (t2 / un) * k1;
    float on = t2 * (sqrtf(u2) / un);
    float on_c = fmaxf(on, FEPS);
    if (on_c > MAXN) k2 *= MAXN / on_c;
    float4 o;
    o.x = k2 * rs.x; o.y = k2 * rs.y; o.z = k2 * rs.z; o.w = k2 * rs.w;
    reinterpret_cast<float4*>(out)[(size_t)row * 16 + fl] = o;
}

// block = bucket (128 rows): in-LDS counting sort by row, then per-row
// REGISTER accumulation (no atomic RMW in hot loop), fp16 gathers (8B/lane).
__global__ __launch_bounds__(256) void kagg2(
    const int* __restrict__ gcnt, const int2* __restrict__ binned,
    const __half* __restrict__ xth, float* __restrict__ out, int n_nodes) {
    __shared__ int hist[BK], offs[BK], cur[BK];
    __shared__ int2 srt[BCAP];
    const int t = threadIdx.x;
    const int b = blockIdx.x;
    for (int i = t; i < BK; i += 256) hist[i] = 0;
    __syncthreads();
    const int nrec = min(gcnt[b], BCAP);
    const int2* rec = binned + (size_t)b * BCAP;
    int2 rc[BCAP / 256];
    #pragma unroll
    for (int i = 0; i < BCAP / 256; ++i) {
        int j = i * 256 + t;
        if (j < nrec) {
            rc[i] = rec[j];
            atomicAdd(&hist[rc[i].x >> 17], 1);
        }
    }
    __syncthreads();
    if (t < 64) {                         // scan 128 counters with one wave
        int v = hist[t];
        int s = wave_incl_scan(v);
        offs[t] = s - v;
    }
    __syncthreads();
    if (t < 64) {
        int c = offs[63] + hist[63];
        int v = hist[64 + t];
        int s = wave_incl_scan(v);
        offs[64 + t] = c + s - v;
    }
    __syncthreads();
    for (int i = t; i < BK; i += 256) cur[i] = offs[i];
    __syncthreads();
    #pragma unroll
    for (int i = 0; i < BCAP / 256; ++i) {
        int j = i * 256 + t;
        if (j < nrec) {
            int lr = rc[i].x >> 17;
            int p = atomicAdd(&cur[lr], 1);
            srt[p] = make_int2(rc[i].x & 0x1FFFF, rc[i].y);
        }
    }
    __syncthreads();

    const int g = t >> 4, fl = t & 15;    // 16 groups x 16 lanes
    #pragma unroll
    for (int it = 0; it < BK / 16; ++it) {
        int lr = it * 16 + g;
        int row = b * BK + lr;
        if (row >= n_nodes) continue;
        int beg = offs[lr], end = beg + hist[lr];
        float4 acc = make_float4(0.f, 0.f, 0.f, 0.f);
        int j = beg;
        for (; j + 1 < end; j += 2) {     // 2-deep gather pipelining
            int2 e0 = srt[j], e1 = srt[j + 1];          // LDS broadcast
            float2 r0 = *reinterpret_cast<const float2*>(
                xth + (size_t)e0.x * DD + fl * 4);
            float2 r1 = *reinterpret_cast<const float2*>(
                xth + (size_t)e1.x * DD + fl * 4);
            float w0 = __int_as_float(e0.y), w1 = __int_as_float(e1.y);
            float2 a0 = __half22float2(*reinterpret_cast<__half2*>(&r0.x));
            float2 a1 = __half22float2(*reinterpret_cast<__half2*>(&r0.y));
            float2 b0 = __half22float2(*reinterpret_cast<__half2*>(&r1.x));
            float2 b1 = __half22float2(*reinterpret_cast<__half2*>(&r1.y));
            acc.x = fmaf(w0, a0.x, acc.x); acc.y = fmaf(w0, a0.y, acc.y);
            acc.z = fmaf(w0, a1.x, acc.z); acc.w = fmaf(w0, a1.y, acc.w);
            acc.x = fmaf(w1, b0.x, acc.x); acc.y = fmaf(w1, b0.y, acc.y);
            acc.z = fmaf(w1, b1.x, acc.z); acc.w = fmaf(w1, b1.y, acc.w);
        }
        if (j < end) {
            int2 e = srt[j];
            float2 r0 = *reinterpret_cast<const float2*>(
                xth + (size_t)e.x * DD + fl * 4);
            float w0 = __int_as_float(e.y);
            float2 a0 = __half22float2(*reinterpret_cast<__half2*>(&r0.x));
            float2 a1 = __half22float2(*reinterpret_cast<__half2*>(&r0.y));
            acc.x = fmaf(w0, a0.x, acc.x); acc.y = fmaf(w0, a0.y, acc.y);
            acc.z = fmaf(w0, a1.x, acc.z); acc.w = fmaf(w0, a1.y, acc.w);
        }
        agg_epilogue(acc, row, fl, out);
    }
}

extern "C" void kernel_launch(void* const* d_in, const int* in_sizes, int n_in,
                              void* d_out, int out_size, void* d_ws, size_t ws_size,
                              hipStream_t stream) {
    const float* x     = (const float*)d_in[0];
    const float* W     = (const float*)d_in[1];
    const float* b     = (const float*)d_in[2];
    const int*   erow  = (const int*)d_in[3];
    const int*   ecol  = (const int*)d_in[4];
    const float* eval_ = (const float*)d_in[5];
    const int n_nodes = in_sizes[0] / DD;   // 100000
    const int n_edges = in_sizes[3];        // 800000
    float* out = (float*)d_out;

    const int NBKT = (n_nodes + BK - 1) / BK;           // 782 (<= NBKT_MAX)

    // ws layout: binned | xth | hbuf | gcnt   (~25.7 MB total)
    int2*   binned = (int2*)d_ws;                       // NBKT*BCAP int2
    __half* xth    = (__half*)(binned + (size_t)NBKT * BCAP);
    float*  hbuf   = (float*)(xth + (size_t)n_nodes * DD);
    int*    gcnt   = (int*)(hbuf + 80);

    const int nbB = (n_edges + CHUNK - 1) / CHUNK;      // 98
    const int nbL = (n_nodes + DD - 1) / DD;            // 1563

    hipMemsetAsync(gcnt, 0, NBKT_MAX * sizeof(int), stream);
    khb_kernel<<<1, 64, 0, stream>>>(b, hbuf);
    kbin<<<nbB, 512, 0, stream>>>(erow, ecol, eval_, gcnt, binned, NBKT, n_edges);
    klinear<<<nbL, 512, 0, stream>>>(x, W, hbuf, xth, n_nodes);
    kagg2<<<NBKT, 256, 0, stream>>>(gcnt, binned, xth, out, n_nodes);
}

// Round 9
// 148.801 us; speedup vs baseline: 3.2358x; 1.0847x over previous
//
#include <hip/hip_runtime.h>
#include <hip/hip_fp16.h>
#include <math.h>

#define DD 64
#define BK 128            // rows per agg bucket (bucket = row >> 7)
#define BCAP 2048         // records per bucket (mean ~1023; +32 sigma)
#define NBKT_MAX 800
#define CHUNK 8192        // edges per kbin block (16 per thread, 512 threads)
constexpr float FEPS = 1e-15f;
constexpr float MAXN = 1.0f - 4e-3f;   // Poincare-ball projection radius (c=1)

__device__ __forceinline__ float wsum(float v) {
    v += __shfl_xor(v, 32);
    v += __shfl_xor(v, 16);
    v += __shfl_xor(v, 8);
    v += __shfl_xor(v, 4);
    v += __shfl_xor(v, 2);
    v += __shfl_xor(v, 1);
    return v;
}

__device__ __forceinline__ int wave_incl_scan(int v) {
    int lane = threadIdx.x & 63;
    #pragma unroll
    for (int d = 1; d < 64; d <<= 1) {
        int t = __shfl_up(v, d);
        if (lane >= d) v += t;
    }
    return v;
}

__device__ __forceinline__ float artanh_c(float x) {
    x = fminf(fmaxf(x, -1.f + 1e-7f), 1.f - 1e-7f);
    return 0.5f * logf((1.f + x) / (1.f - x));
}

struct SmemLin {
    float tile[DD * 65];     // 16640 B
    float red0[8][DD];       // 2048 B
    float red1[8][DD];       // 2048 B
    float hb[66];            // bias vector + |hb|^2
};
struct SmemBin {
    int lcnt[NBKT_MAX];
    int goff[NBKT_MAX];
};

// Fused dispatch: blocks [0,nbL) = linear transform; [nbL, nbL+nbB) = edge binning.
// The two halves are data-independent; binning's memory work overlaps the
// linear part's latency stalls.
__global__ __launch_bounds__(512) void kfused(
    const float* __restrict__ x, const float* __restrict__ W,
    const float* __restrict__ bvec, __half* __restrict__ xth,
    const int* __restrict__ erow, const int* __restrict__ ecol,
    const float* __restrict__ eval_, int* __restrict__ gcnt,
    int2* __restrict__ binned, int nbkt, int n_edges, int n_nodes, int nbL) {
    __shared__ union { SmemLin lin; SmemBin bin; } sm;
    const int t = threadIdx.x;

    if ((int)blockIdx.x >= nbL) {
        // ---------------- kbin part ----------------
        const int eb = ((int)blockIdx.x - nbL) * CHUNK;
        for (int i = t; i < nbkt; i += 512) sm.bin.lcnt[i] = 0;
        __syncthreads();
        int rk[16];
        #pragma unroll
        for (int i = 0; i < 16; ++i) {
            int e = eb + i * 512 + t;
            rk[i] = -1;
            if (e < n_edges) {
                int r = erow[e];
                int bkt = r >> 7;
                int rank = atomicAdd(&sm.bin.lcnt[bkt], 1);   // < 8192: 13 bits
                rk[i] = (bkt << 20) | ((r & (BK - 1)) << 13) | rank;
            }
        }
        __syncthreads();
        for (int i = t; i < nbkt; i += 512) {
            int c = sm.bin.lcnt[i];
            if (c > 0) sm.bin.goff[i] = atomicAdd(&gcnt[i], c);  // reserve range
        }
        __syncthreads();
        #pragma unroll
        for (int i = 0; i < 16; ++i) {
            int e = eb + i * 512 + t;
            if (e >= n_edges) continue;
            int bkt = rk[i] >> 20, lr = (rk[i] >> 13) & 127, rank = rk[i] & 8191;
            int pos = sm.bin.goff[bkt] + rank;
            if (pos < BCAP)
                binned[(size_t)bkt * BCAP + pos] =
                    make_int2((lr << 17) | ecol[e], __float_as_int(eval_[e]));
        }
        return;
    }

    // ---------------- klinear part ----------------
    const int lane = t & 63;
    const int w = t >> 6;
    const int n0 = blockIdx.x * DD;

    #pragma unroll
    for (int rep = 0; rep < 2; ++rep) {
        int i = rep * 512 + t;
        int nd = i >> 4, q = i & 15;
        int node = n0 + nd;
        const float4* src = reinterpret_cast<const float4*>(
            x + (size_t)(node < n_nodes ? node : 0) * DD);
        float4 v = src[q];
        float* d = &sm.lin.tile[nd * 65 + q * 4];
        d[0] = v.x; d[1] = v.y; d[2] = v.z; d[3] = v.w;
    }
    if (t < 64) {          // wave 0: hyperbolic bias hb = proj(expmap0(b))
        float bv = bvec[t];
        float n2 = wsum(bv * bv);
        float n = fmaxf(sqrtf(n2), FEPS);
        float th = tanhf(n);
        float p = th * (bv / n);
        float pn = th * (sqrtf(n2) / n);
        float pn_c = fmaxf(pn, FEPS);
        if (pn_c > MAXN) p *= MAXN / pn_c;
        sm.lin.hb[t] = p;
        float p2 = wsum(p * p);
        if (t == 0) sm.lin.hb[DD] = p2;
    }
    __syncthreads();

    const int jbase = __builtin_amdgcn_readfirstlane(w) * 8;
    float mx[8] = {0.f, 0.f, 0.f, 0.f, 0.f, 0.f, 0.f, 0.f};
    float xn2 = 0.f;
    #pragma unroll
    for (int kk = 0; kk < 4; ++kk) {
        float xv[16];
        #pragma unroll
        for (int ki = 0; ki < 16; ++ki)
            xv[ki] = sm.lin.tile[lane * 65 + kk * 16 + ki];
        #pragma unroll
        for (int ki = 0; ki < 16; ++ki)
            xn2 = fmaf(xv[ki], xv[ki], xn2);
        #pragma unroll
        for (int jj = 0; jj < 8; ++jj) {
            const float* Wr = W + (jbase + jj) * DD + kk * 16;   // uniform -> s_load
            float a = mx[jj];
            #pragma unroll
            for (int ki = 0; ki < 16; ++ki) a = fmaf(Wr[ki], xv[ki], a);
            mx[jj] = a;
        }
    }
    float mx2p = 0.f, mxhp = 0.f;
    #pragma unroll
    for (int jj = 0; jj < 8; ++jj) {
        mx2p = fmaf(mx[jj], mx[jj], mx2p);
        mxhp = fmaf(mx[jj], sm.lin.hb[jbase + jj], mxhp);
    }
    sm.lin.red0[w][lane] = mx2p;
    sm.lin.red1[w][lane] = mxhp;
    __syncthreads();
    float mx2 = 0.f, mxh = 0.f;
    #pragma unroll
    for (int ww = 0; ww < 8; ++ww) {     // identical order -> bitwise-equal in all waves
        mx2 += sm.lin.red0[ww][lane];
        mxh += sm.lin.red1[ww][lane];
    }

    float xn = fmaxf(sqrtf(xn2), FEPS);
    float mxn = fmaxf(sqrtf(mx2), FEPS);
    float th = tanhf((mxn / xn) * artanh_c(xn));
    float sres = (mx2 == 0.f) ? 0.f : th / mxn;
    float rn = (mx2 == 0.f) ? 0.f : th * (sqrtf(mx2) / mxn);
    float rn_c = fmaxf(rn, FEPS);
    float s1 = (rn_c > MAXN) ? sres * (MAXN / rn_c) : sres;
    float x2r = s1 * s1 * mx2;
    float xy = s1 * mxh;
    float y2 = sm.lin.hb[DD];
    float ca = 1.f + 2.f * xy + y2;
    float cb = 1.f - x2r;
    float rden = 1.f / fmaxf(1.f + 2.f * xy + x2r * y2, FEPS);
    float al = ca * s1 * rden;
    float be = cb * rden;
    float h2 = al * al * mx2 + 2.f * al * be * mxh + be * be * y2;
    float hn = fmaxf(sqrtf(h2), FEPS);
    float sh = 1.f;
    if (hn > MAXN) { sh = MAXN / hn; hn = MAXN; }
    float su = sh * (artanh_c(hn) / hn);
    float A = su * al, B = su * be;

    #pragma unroll
    for (int jj = 0; jj < 8; ++jj)
        sm.lin.tile[lane * 65 + jbase + jj] =
            fmaf(A, mx[jj], B * sm.lin.hb[jbase + jj]);
    __syncthreads();

    // coalesced fp16 store (8B per thread-item)
    uint2* dst = reinterpret_cast<uint2*>(xth + (size_t)n0 * DD);
    #pragma unroll
    for (int rep = 0; rep < 2; ++rep) {
        int i = rep * 512 + t;
        int nd = i >> 4, q = i & 15;
        if (n0 + nd < n_nodes) {
            const float* s = &sm.lin.tile[nd * 65 + q * 4];
            __half2 h0 = __floats2half2_rn(s[0], s[1]);
            __half2 h1 = __floats2half2_rn(s[2], s[3]);
            uint2 o;
            o.x = *reinterpret_cast<unsigned int*>(&h0);
            o.y = *reinterpret_cast<unsigned int*>(&h1);
            dst[i] = o;
        }
    }
}

// folded epilogue: o = K(n2, sp2) * relu(s)
__device__ __forceinline__ void agg_epilogue(
    float4 acc, int row, int fl, float* __restrict__ out) {
    float4 s;
    s.x = fminf(acc.x, 1e6f); s.y = fminf(acc.y, 1e6f);
    s.z = fminf(acc.z, 1e6f); s.w = fminf(acc.w, 1e6f);
    float4 rs;
    rs.x = fmaxf(s.x, 0.f); rs.y = fmaxf(s.y, 0.f);
    rs.z = fmaxf(s.z, 0.f); rs.w = fmaxf(s.w, 0.f);
    float n2p = s.x * s.x + s.y * s.y + s.z * s.z + s.w * s.w;
    float sp2p = rs.x * rs.x + rs.y * rs.y + rs.z * rs.z + rs.w * rs.w;
    #pragma unroll
    for (int m = 1; m < 16; m <<= 1) {
        n2p += __shfl_xor(n2p, m);
        sp2p += __shfl_xor(sp2p, m);
    }
    float n = fmaxf(sqrtf(n2p), FEPS);
    float th = tanhf(n);
    float c1 = th / n;
    float pn = th * (sqrtf(n2p) / n);
    float pn_c = fmaxf(pn, FEPS);
    if (pn_c > MAXN) { c1 *= MAXN / pn_c; pn_c = MAXN; }
    float k1 = (artanh_c(pn_c) / pn_c) * c1;
    float u2 = k1 * k1 * sp2p;
    float un = fmaxf(sqrtf(u2), FEPS);
    float t2 = tanhf(un);
    float k2 = (t2 / un) * k1;
    float on = t2 * (sqrtf(u2) / un);
    float on_c = fmaxf(on, FEPS);
    if (on_c > MAXN) k2 *= MAXN / on_c;
    float4 o;
    o.x = k2 * rs.x; o.y = k2 * rs.y; o.z = k2 * rs.z; o.w = k2 * rs.w;
    reinterpret_cast<float4*>(out)[(size_t)row * 16 + fl] = o;
}

// block = bucket (128 rows), 512 threads = 32 groups x 16 lanes.
// In-LDS counting sort by row, then register accumulation, 4-deep gathers.
__global__ __launch_bounds__(512) void kagg2(
    const int* __restrict__ gcnt, const int2* __restrict__ binned,
    const __half* __restrict__ xth, float* __restrict__ out, int n_nodes) {
    __shared__ int hist[BK], offs[BK], cur[BK];
    __shared__ int2 srt[BCAP];
    const int t = threadIdx.x;
    const int b = blockIdx.x;
    for (int i = t; i < BK; i += 512) hist[i] = 0;
    __syncthreads();
    const int nrec = min(gcnt[b], BCAP);
    const int2* rec = binned + (size_t)b * BCAP;
    int2 rc[BCAP / 512];
    #pragma unroll
    for (int i = 0; i < BCAP / 512; ++i) {
        int j = i * 512 + t;
        if (j < nrec) {
            rc[i] = rec[j];
            atomicAdd(&hist[rc[i].x >> 17], 1);
        }
    }
    __syncthreads();
    if (t < 64) {                         // scan 128 counters with one wave
        int v = hist[t];
        int s = wave_incl_scan(v);
        offs[t] = s - v;
    }
    __syncthreads();
    if (t < 64) {
        int c = offs[63] + hist[63];
        int v = hist[64 + t];
        int s = wave_incl_scan(v);
        offs[64 + t] = c + s - v;
    }
    __syncthreads();
    for (int i = t; i < BK; i += 512) cur[i] = offs[i];
    __syncthreads();
    #pragma unroll
    for (int i = 0; i < BCAP / 512; ++i) {
        int j = i * 512 + t;
        if (j < nrec) {
            int lr = rc[i].x >> 17;
            int p = atomicAdd(&cur[lr], 1);
            srt[p] = make_int2(rc[i].x & 0x1FFFF, rc[i].y);
        }
    }
    __syncthreads();

    const int g = t >> 4, fl = t & 15;    // 32 groups x 16 lanes
    #pragma unroll
    for (int it = 0; it < BK / 32; ++it) {
        int lr = it * 32 + g;
        int row = b * BK + lr;
        if (row >= n_nodes) continue;
        int beg = offs[lr], end = beg + hist[lr];
        float4 acc = make_float4(0.f, 0.f, 0.f, 0.f);
        int j = beg;
        for (; j + 3 < end; j += 4) {     // 4-deep gather pipelining
            int2 e0 = srt[j], e1 = srt[j + 1], e2 = srt[j + 2], e3 = srt[j + 3];
            float2 r0 = *reinterpret_cast<const float2*>(xth + (size_t)e0.x * DD + fl * 4);
            float2 r1 = *reinterpret_cast<const float2*>(xth + (size_t)e1.x * DD + fl * 4);
            float2 r2 = *reinterpret_cast<const float2*>(xth + (size_t)e2.x * DD + fl * 4);
            float2 r3 = *reinterpret_cast<const float2*>(xth + (size_t)e3.x * DD + fl * 4);
            float w0 = __int_as_float(e0.y), w1 = __int_as_float(e1.y);
            float w2 = __int_as_float(e2.y), w3 = __int_as_float(e3.y);
            float2 a0 = __half22float2(*reinterpret_cast<__half2*>(&r0.x));
            float2 a1 = __half22float2(*reinterpret_cast<__half2*>(&r0.y));
            float2 b0 = __half22float2(*reinterpret_cast<__half2*>(&r1.x));
            float2 b1 = __half22float2(*reinterpret_cast<__half2*>(&r1.y));
            float2 c0 = __half22float2(*reinterpret_cast<__half2*>(&r2.x));
            float2 c1 = __half22float2(*reinterpret_cast<__half2*>(&r2.y));
            float2 d0 = __half22float2(*reinterpret_cast<__half2*>(&r3.x));
            float2 d1 = __half22float2(*reinterpret_cast<__half2*>(&r3.y));
            acc.x = fmaf(w0, a0.x, acc.x); acc.y = fmaf(w0, a0.y, acc.y);
            acc.z = fmaf(w0, a1.x, acc.z); acc.w = fmaf(w0, a1.y, acc.w);
            acc.x = fmaf(w1, b0.x, acc.x); acc.y = fmaf(w1, b0.y, acc.y);
            acc.z = fmaf(w1, b1.x, acc.z); acc.w = fmaf(w1, b1.y, acc.w);
            acc.x = fmaf(w2, c0.x, acc.x); acc.y = fmaf(w2, c0.y, acc.y);
            acc.z = fmaf(w2, c1.x, acc.z); acc.w = fmaf(w2, c1.y, acc.w);
            acc.x = fmaf(w3, d0.x, acc.x); acc.y = fmaf(w3, d0.y, acc.y);
            acc.z = fmaf(w3, d1.x, acc.z); acc.w = fmaf(w3, d1.y, acc.w);
        }
        for (; j < end; ++j) {
            int2 e = srt[j];
            float2 r0 = *reinterpret_cast<const float2*>(xth + (size_t)e.x * DD + fl * 4);
            float w0 = __int_as_float(e.y);
            float2 a0 = __half22float2(*reinterpret_cast<__half2*>(&r0.x));
            float2 a1 = __half22float2(*reinterpret_cast<__half2*>(&r0.y));
            acc.x = fmaf(w0, a0.x, acc.x); acc.y = fmaf(w0, a0.y, acc.y);
            acc.z = fmaf(w0, a1.x, acc.z); acc.w = fmaf(w0, a1.y, acc.w);
        }
        agg_epilogue(acc, row, fl, out);
    }
}

extern "C" void kernel_launch(void* const* d_in, const int* in_sizes, int n_in,
                              void* d_out, int out_size, void* d_ws, size_t ws_size,
                              hipStream_t stream) {
    const float* x     = (const float*)d_in[0];
    const float* W     = (const float*)d_in[1];
    const float* b     = (const float*)d_in[2];
    const int*   erow  = (const int*)d_in[3];
    const int*   ecol  = (const int*)d_in[4];
    const float* eval_ = (const float*)d_in[5];
    const int n_nodes = in_sizes[0] / DD;   // 100000
    const int n_edges = in_sizes[3];        // 800000
    float* out = (float*)d_out;

    const int NBKT = (n_nodes + BK - 1) / BK;           // 782 (<= NBKT_MAX)

    // ws layout: binned | xth | gcnt   (~25.6 MB total)
    int2*   binned = (int2*)d_ws;                       // NBKT*BCAP int2
    __half* xth    = (__half*)(binned + (size_t)NBKT * BCAP);
    int*    gcnt   = (int*)(xth + (size_t)n_nodes * DD);

    const int nbB = (n_edges + CHUNK - 1) / CHUNK;      // 98
    const int nbL = (n_nodes + DD - 1) / DD;            // 1563

    hipMemsetAsync(gcnt, 0, NBKT_MAX * sizeof(int), stream);
    kfused<<<nbL + nbB, 512, 0, stream>>>(x, W, b, xth, erow, ecol, eval_,
                                          gcnt, binned, NBKT, n_edges, n_nodes, nbL);
    kagg2<<<NBKT, 512, 0, stream>>>(gcnt, binned, xth, out, n_nodes);
}

// Round 10
// 138.855 us; speedup vs baseline: 3.4676x; 1.0716x over previous
//
#include <hip/hip_runtime.h>
#include <hip/hip_fp16.h>
#include <math.h>

#define DD 64
#define BK 128            // rows per agg bucket (bucket = row >> 7)
#define BCAP 2048         // records per bucket (mean ~1023; +32 sigma)
#define NBKT_MAX 800
#define CHUNK 2048        // edges per bin block (4 per thread, 512 threads)
constexpr float FEPS = 1e-15f;
constexpr float MAXN = 1.0f - 4e-3f;   // Poincare-ball projection radius (c=1)

__device__ __forceinline__ float wsum(float v) {
    v += __shfl_xor(v, 32);
    v += __shfl_xor(v, 16);
    v += __shfl_xor(v, 8);
    v += __shfl_xor(v, 4);
    v += __shfl_xor(v, 2);
    v += __shfl_xor(v, 1);
    return v;
}

__device__ __forceinline__ int wave_incl_scan(int v) {
    int lane = threadIdx.x & 63;
    #pragma unroll
    for (int d = 1; d < 64; d <<= 1) {
        int t = __shfl_up(v, d);
        if (lane >= d) v += t;
    }
    return v;
}

__device__ __forceinline__ float artanh_c(float x) {
    x = fminf(fmaxf(x, -1.f + 1e-7f), 1.f - 1e-7f);
    return 0.5f * logf((1.f + x) / (1.f - x));
}

struct SmemLin {
    float tile[DD * 65];     // 16640 B x tile (pitch 65: conflict-free)
    float red0[8][DD];       // per-wave partial mx2
    float red1[8][DD];       // per-wave partial <mx,hb>
    float hb[66];            // bias vector + |hb|^2
    float Ab[DD], Bb[DD];    // per-node scalar-chain results (wave0 -> all)
};
struct SmemBin {
    int lcnt[NBKT_MAX];
    int goff[NBKT_MAX];
};

// Fused dispatch. Blocks [0,nbB) = edge binning (FIRST, so they co-schedule
// with the linear blocks instead of forming a serialized tail);
// blocks [nbB, nbB+nbL) = linear transform.
__global__ __launch_bounds__(512) void kfused(
    const float* __restrict__ x, const float* __restrict__ W,
    const float* __restrict__ bvec, __half* __restrict__ xth,
    const int* __restrict__ erow, const int* __restrict__ ecol,
    const float* __restrict__ eval_, int* __restrict__ gcnt,
    int2* __restrict__ binned, int nbkt, int n_edges, int n_nodes, int nbB) {
    __shared__ union { SmemLin lin; SmemBin bin; } sm;
    const int t = threadIdx.x;

    if ((int)blockIdx.x < nbB) {
        // ---------------- bin part (short blocks, dispatched first) ----------------
        const int eb = blockIdx.x * CHUNK;
        for (int i = t; i < nbkt; i += 512) sm.bin.lcnt[i] = 0;
        __syncthreads();
        int rk[4];
        #pragma unroll
        for (int i = 0; i < 4; ++i) {
            int e = eb + i * 512 + t;
            rk[i] = -1;
            if (e < n_edges) {
                int r = erow[e];
                int bkt = r >> 7;
                int rank = atomicAdd(&sm.bin.lcnt[bkt], 1);   // < 2048: 13 bits ok
                rk[i] = (bkt << 20) | ((r & (BK - 1)) << 13) | rank;
            }
        }
        __syncthreads();
        for (int i = t; i < nbkt; i += 512) {
            int c = sm.bin.lcnt[i];
            if (c > 0) sm.bin.goff[i] = atomicAdd(&gcnt[i], c);  // reserve range
        }
        __syncthreads();
        #pragma unroll
        for (int i = 0; i < 4; ++i) {
            int e = eb + i * 512 + t;
            if (e >= n_edges) continue;
            int bkt = rk[i] >> 20, lr = (rk[i] >> 13) & 127, rank = rk[i] & 8191;
            int pos = sm.bin.goff[bkt] + rank;
            if (pos < BCAP)
                binned[(size_t)bkt * BCAP + pos] =
                    make_int2((lr << 17) | ecol[e], __float_as_int(eval_[e]));
        }
        return;
    }

    // ---------------- linear part ----------------
    const int lane = t & 63;
    const int w = t >> 6;
    const int n0 = ((int)blockIdx.x - nbB) * DD;

    #pragma unroll
    for (int rep = 0; rep < 2; ++rep) {
        int i = rep * 512 + t;
        int nd = i >> 4, q = i & 15;
        int node = n0 + nd;
        const float4* src = reinterpret_cast<const float4*>(
            x + (size_t)(node < n_nodes ? node : 0) * DD);
        float4 v = src[q];
        float* d = &sm.lin.tile[nd * 65 + q * 4];
        d[0] = v.x; d[1] = v.y; d[2] = v.z; d[3] = v.w;
    }
    if (t < 64) {          // wave 0: hyperbolic bias hb = proj(expmap0(b))
        float bv = bvec[t];
        float n2 = wsum(bv * bv);
        float n = fmaxf(sqrtf(n2), FEPS);
        float th = tanhf(n);
        float p = th * (bv / n);
        float pn = th * (sqrtf(n2) / n);
        float pn_c = fmaxf(pn, FEPS);
        if (pn_c > MAXN) p *= MAXN / pn_c;
        sm.lin.hb[t] = p;
        float p2 = wsum(p * p);
        if (t == 0) sm.lin.hb[DD] = p2;
    }
    __syncthreads();

    const int jbase = __builtin_amdgcn_readfirstlane(w) * 8;
    float mx[8] = {0.f, 0.f, 0.f, 0.f, 0.f, 0.f, 0.f, 0.f};
    float xn2 = 0.f;
    #pragma unroll
    for (int kk = 0; kk < 4; ++kk) {
        float xv[16];
        #pragma unroll
        for (int ki = 0; ki < 16; ++ki)
            xv[ki] = sm.lin.tile[lane * 65 + kk * 16 + ki];
        #pragma unroll
        for (int ki = 0; ki < 16; ++ki)
            xn2 = fmaf(xv[ki], xv[ki], xn2);
        #pragma unroll
        for (int jj = 0; jj < 8; ++jj) {
            const float* Wr = W + (jbase + jj) * DD + kk * 16;   // uniform -> s_load
            float a = mx[jj];
            #pragma unroll
            for (int ki = 0; ki < 16; ++ki) a = fmaf(Wr[ki], xv[ki], a);
            mx[jj] = a;
        }
    }
    float mx2p = 0.f, mxhp = 0.f;
    #pragma unroll
    for (int jj = 0; jj < 8; ++jj) {
        mx2p = fmaf(mx[jj], mx[jj], mx2p);
        mxhp = fmaf(mx[jj], sm.lin.hb[jbase + jj], mxhp);
    }
    sm.lin.red0[w][lane] = mx2p;
    sm.lin.red1[w][lane] = mxhp;
    __syncthreads();

    if (t < 64) {          // wave 0 ONLY: per-node scalar chain (was 8x redundant)
        float mx2 = 0.f, mxh = 0.f;
        #pragma unroll
        for (int ww = 0; ww < 8; ++ww) {
            mx2 += sm.lin.red0[ww][t];
            mxh += sm.lin.red1[ww][t];
        }
        float xn = fmaxf(sqrtf(xn2), FEPS);      // wave0's own xn2 (lane=node)
        float mxn = fmaxf(sqrtf(mx2), FEPS);
        float th = tanhf((mxn / xn) * artanh_c(xn));
        float sres = (mx2 == 0.f) ? 0.f : th / mxn;
        float rn = (mx2 == 0.f) ? 0.f : th * (sqrtf(mx2) / mxn);
        float rn_c = fmaxf(rn, FEPS);
        float s1 = (rn_c > MAXN) ? sres * (MAXN / rn_c) : sres;
        float x2r = s1 * s1 * mx2;
        float xy = s1 * mxh;
        float y2 = sm.lin.hb[DD];
        float ca = 1.f + 2.f * xy + y2;
        float cb = 1.f - x2r;
        float rden = 1.f / fmaxf(1.f + 2.f * xy + x2r * y2, FEPS);
        float al = ca * s1 * rden;
        float be = cb * rden;
        float h2 = al * al * mx2 + 2.f * al * be * mxh + be * be * y2;
        float hn = fmaxf(sqrtf(h2), FEPS);
        float sh = 1.f;
        if (hn > MAXN) { sh = MAXN / hn; hn = MAXN; }
        float su = sh * (artanh_c(hn) / hn);
        sm.lin.Ab[t] = su * al;
        sm.lin.Bb[t] = su * be;
    }
    __syncthreads();

    // direct fp16 store: thread owns (node=lane, j in [jbase, jbase+8)) = 16 B
    int node = n0 + lane;
    if (node < n_nodes) {
        float A = sm.lin.Ab[lane], B = sm.lin.Bb[lane];
        float u[8];
        #pragma unroll
        for (int jj = 0; jj < 8; ++jj)
            u[jj] = fmaf(A, mx[jj], B * sm.lin.hb[jbase + jj]);
        __half2 p0 = __floats2half2_rn(u[0], u[1]);
        __half2 p1 = __floats2half2_rn(u[2], u[3]);
        __half2 p2 = __floats2half2_rn(u[4], u[5]);
        __half2 p3 = __floats2half2_rn(u[6], u[7]);
        uint4 o;
        o.x = *reinterpret_cast<unsigned int*>(&p0);
        o.y = *reinterpret_cast<unsigned int*>(&p1);
        o.z = *reinterpret_cast<unsigned int*>(&p2);
        o.w = *reinterpret_cast<unsigned int*>(&p3);
        // byte offset = node*128 + 16*w -> 16B aligned; waves 0..7 fill the row
        *reinterpret_cast<uint4*>(xth + (size_t)node * DD + jbase) = o;
    }
}

// folded epilogue: o = K(n2, sp2) * relu(s)
__device__ __forceinline__ void agg_epilogue(
    float4 acc, int row, int fl, float* __restrict__ out) {
    float4 s;
    s.x = fminf(acc.x, 1e6f); s.y = fminf(acc.y, 1e6f);
    s.z = fminf(acc.z, 1e6f); s.w = fminf(acc.w, 1e6f);
    float4 rs;
    rs.x = fmaxf(s.x, 0.f); rs.y = fmaxf(s.y, 0.f);
    rs.z = fmaxf(s.z, 0.f); rs.w = fmaxf(s.w, 0.f);
    float n2p = s.x * s.x + s.y * s.y + s.z * s.z + s.w * s.w;
    float sp2p = rs.x * rs.x + rs.y * rs.y + rs.z * rs.z + rs.w * rs.w;
    #pragma unroll
    for (int m = 1; m < 16; m <<= 1) {
        n2p += __shfl_xor(n2p, m);
        sp2p += __shfl_xor(sp2p, m);
    }
    float n = fmaxf(sqrtf(n2p), FEPS);
    float th = tanhf(n);
    float c1 = th / n;
    float pn = th * (sqrtf(n2p) / n);
    float pn_c = fmaxf(pn, FEPS);
    if (pn_c > MAXN) { c1 *= MAXN / pn_c; pn_c = MAXN; }
    float k1 = (artanh_c(pn_c) / pn_c) * c1;
    float u2 = k1 * k1 * sp2p;
    float un = fmaxf(sqrtf(u2), FEPS);
    float t2 = tanhf(un);
    float k2 = (t2 / un) * k1;
    float on = t2 * (sqrtf(u2) / un);
    float on_c = fmaxf(on, FEPS);
    if (on_c > MAXN) k2 *= MAXN / on_c;
    float4 o;
    o.x = k2 * rs.x; o.y = k2 * rs.y; o.z = k2 * rs.z; o.w = k2 * rs.w;
    reinterpret_cast<float4*>(out)[(size_t)row * 16 + fl] = o;
}

// block = bucket (128 rows), 512 threads = 32 groups x 16 lanes.
// In-LDS counting sort by row, then register accumulation, 4-deep gathers.
__global__ __launch_bounds__(512) void kagg2(
    const int* __restrict__ gcnt, const int2* __restrict__ binned,
    const __half* __restrict__ xth, float* __restrict__ out, int n_nodes) {
    __shared__ int hist[BK], offs[BK], cur[BK];
    __shared__ int2 srt[BCAP];
    const int t = threadIdx.x;
    const int b = blockIdx.x;
    for (int i = t; i < BK; i += 512) hist[i] = 0;
    __syncthreads();
    const int nrec = min(gcnt[b], BCAP);
    const int2* rec = binned + (size_t)b * BCAP;
    int2 rc[BCAP / 512];
    #pragma unroll
    for (int i = 0; i < BCAP / 512; ++i) {
        int j = i * 512 + t;
        if (j < nrec) {
            rc[i] = rec[j];
            atomicAdd(&hist[rc[i].x >> 17], 1);
        }
    }
    __syncthreads();
    if (t < 64) {                         // scan 128 counters with one wave
        int v = hist[t];
        int s = wave_incl_scan(v);
        offs[t] = s - v;
    }
    __syncthreads();
    if (t < 64) {
        int c = offs[63] + hist[63];
        int v = hist[64 + t];
        int s = wave_incl_scan(v);
        offs[64 + t] = c + s - v;
    }
    __syncthreads();
    for (int i = t; i < BK; i += 512) cur[i] = offs[i];
    __syncthreads();
    #pragma unroll
    for (int i = 0; i < BCAP / 512; ++i) {
        int j = i * 512 + t;
        if (j < nrec) {
            int lr = rc[i].x >> 17;
            int p = atomicAdd(&cur[lr], 1);
            srt[p] = make_int2(rc[i].x & 0x1FFFF, rc[i].y);
        }
    }
    __syncthreads();

    const int g = t >> 4, fl = t & 15;    // 32 groups x 16 lanes
    #pragma unroll
    for (int it = 0; it < BK / 32; ++it) {
        int lr = it * 32 + g;
        int row = b * BK + lr;
        if (row >= n_nodes) continue;
        int beg = offs[lr], end = beg + hist[lr];
        float4 acc = make_float4(0.f, 0.f, 0.f, 0.f);
        int j = beg;
        for (; j + 3 < end; j += 4) {     // 4-deep gather pipelining
            int2 e0 = srt[j], e1 = srt[j + 1], e2 = srt[j + 2], e3 = srt[j + 3];
            float2 r0 = *reinterpret_cast<const float2*>(xth + (size_t)e0.x * DD + fl * 4);
            float2 r1 = *reinterpret_cast<const float2*>(xth + (size_t)e1.x * DD + fl * 4);
            float2 r2 = *reinterpret_cast<const float2*>(xth + (size_t)e2.x * DD + fl * 4);
            float2 r3 = *reinterpret_cast<const float2*>(xth + (size_t)e3.x * DD + fl * 4);
            float w0 = __int_as_float(e0.y), w1 = __int_as_float(e1.y);
            float w2 = __int_as_float(e2.y), w3 = __int_as_float(e3.y);
            float2 a0 = __half22float2(*reinterpret_cast<__half2*>(&r0.x));
            float2 a1 = __half22float2(*reinterpret_cast<__half2*>(&r0.y));
            float2 b0 = __half22float2(*reinterpret_cast<__half2*>(&r1.x));
            float2 b1 = __half22float2(*reinterpret_cast<__half2*>(&r1.y));
            float2 c0 = __half22float2(*reinterpret_cast<__half2*>(&r2.x));
            float2 c1 = __half22float2(*reinterpret_cast<__half2*>(&r2.y));
            float2 d0 = __half22float2(*reinterpret_cast<__half2*>(&r3.x));
            float2 d1 = __half22float2(*reinterpret_cast<__half2*>(&r3.y));
            acc.x = fmaf(w0, a0.x, acc.x); acc.y = fmaf(w0, a0.y, acc.y);
            acc.z = fmaf(w0, a1.x, acc.z); acc.w = fmaf(w0, a1.y, acc.w);
            acc.x = fmaf(w1, b0.x, acc.x); acc.y = fmaf(w1, b0.y, acc.y);
            acc.z = fmaf(w1, b1.x, acc.z); acc.w = fmaf(w1, b1.y, acc.w);
            acc.x = fmaf(w2, c0.x, acc.x); acc.y = fmaf(w2, c0.y, acc.y);
            acc.z = fmaf(w2, c1.x, acc.z); acc.w = fmaf(w2, c1.y, acc.w);
            acc.x = fmaf(w3, d0.x, acc.x); acc.y = fmaf(w3, d0.y, acc.y);
            acc.z = fmaf(w3, d1.x, acc.z); acc.w = fmaf(w3, d1.y, acc.w);
        }
        for (; j < end; ++j) {
            int2 e = srt[j];
            float2 r0 = *reinterpret_cast<const float2*>(xth + (size_t)e.x * DD + fl * 4);
            float w0 = __int_as_float(e.y);
            float2 a0 = __half22float2(*reinterpret_cast<__half2*>(&r0.x));
            float2 a1 = __half22float2(*reinterpret_cast<__half2*>(&r0.y));
            acc.x = fmaf(w0, a0.x, acc.x); acc.y = fmaf(w0, a0.y, acc.y);
            acc.z = fmaf(w0, a1.x, acc.z); acc.w = fmaf(w0, a1.y, acc.w);
        }
        agg_epilogue(acc, row, fl, out);
    }
}

extern "C" void kernel_launch(void* const* d_in, const int* in_sizes, int n_in,
                              void* d_out, int out_size, void* d_ws, size_t ws_size,
                              hipStream_t stream) {
    const float* x     = (const float*)d_in[0];
    const float* W     = (const float*)d_in[1];
    const float* b     = (const float*)d_in[2];
    const int*   erow  = (const int*)d_in[3];
    const int*   ecol  = (const int*)d_in[4];
    const float* eval_ = (const float*)d_in[5];
    const int n_nodes = in_sizes[0] / DD;   // 100000
    const int n_edges = in_sizes[3];        // 800000
    float* out = (float*)d_out;

    const int NBKT = (n_nodes + BK - 1) / BK;           // 782 (<= NBKT_MAX)

    // ws layout: binned | xth | gcnt   (~25.6 MB total)
    int2*   binned = (int2*)d_ws;                       // NBKT*BCAP int2
    __half* xth    = (__half*)(binned + (size_t)NBKT * BCAP);
    int*    gcnt   = (int*)(xth + (size_t)n_nodes * DD);

    const int nbB = (n_edges + CHUNK - 1) / CHUNK;      // 391
    const int nbL = (n_nodes + DD - 1) / DD;            // 1563

    hipMemsetAsync(gcnt, 0, NBKT_MAX * sizeof(int), stream);
    kfused<<<nbB + nbL, 512, 0, stream>>>(x, W, b, xth, erow, ecol, eval_,
                                          gcnt, binned, NBKT, n_edges, n_nodes, nbB);
    kagg2<<<NBKT, 512, 0, stream>>>(gcnt, binned, xth, out, n_nodes);
}

// Round 11
// 136.285 us; speedup vs baseline: 3.5330x; 1.0189x over previous
//
#include <hip/hip_runtime.h>
#include <hip/hip_fp16.h>
#include <math.h>

#define DD 64
#define BK 128            // rows per agg bucket (bucket = row >> 7)
#define BCAP 2048         // records per bucket (mean ~1023; +32 sigma)
#define NBKT_MAX 800
#define CHUNK 8192        // edges per bin block (16 per thread, 512 threads)
constexpr float FEPS = 1e-15f;
constexpr float MAXN = 1.0f - 4e-3f;   // Poincare-ball projection radius (c=1)

__device__ __forceinline__ float wsum(float v) {
    v += __shfl_xor(v, 32);
    v += __shfl_xor(v, 16);
    v += __shfl_xor(v, 8);
    v += __shfl_xor(v, 4);
    v += __shfl_xor(v, 2);
    v += __shfl_xor(v, 1);
    return v;
}

__device__ __forceinline__ int wave_incl_scan(int v) {
    int lane = threadIdx.x & 63;
    #pragma unroll
    for (int d = 1; d < 64; d <<= 1) {
        int t = __shfl_up(v, d);
        if (lane >= d) v += t;
    }
    return v;
}

__device__ __forceinline__ float artanh_c(float x) {
    x = fminf(fmaxf(x, -1.f + 1e-7f), 1.f - 1e-7f);
    return 0.5f * logf((1.f + x) / (1.f - x));
}

struct SmemLin {
    float tile[DD * 65];     // x tile (pitch 65: conflict-free)
    float red0[8][DD];       // per-wave partial mx2
    float red1[8][DD];       // per-wave partial <mx,hb>
    float hb[66];            // bias vector + |hb|^2
    float Ab[DD], Bb[DD];    // per-node scalar-chain results (wave0 -> all)
};
struct SmemBin {
    int lcnt[NBKT_MAX];
    int goff[NBKT_MAX];
};

// Fused dispatch. Blocks [0,nbB) = edge binning (dispatched first so they
// co-schedule with the linear blocks); blocks [nbB, nbB+nbL) = linear.
__global__ __launch_bounds__(512) void kfused(
    const float* __restrict__ x, const float* __restrict__ W,
    const float* __restrict__ bvec, __half* __restrict__ xth,
    const int* __restrict__ erow, const int* __restrict__ ecol,
    const float* __restrict__ eval_, int* __restrict__ gcnt,
    int2* __restrict__ binned, int nbkt, int n_edges, int n_nodes, int nbB) {
    __shared__ union { SmemLin lin; SmemBin bin; } sm;
    const int t = threadIdx.x;

    if ((int)blockIdx.x < nbB) {
        // ---------------- bin part (CHUNK=8192: run length ~10.5) ----------------
        const int eb = blockIdx.x * CHUNK;
        for (int i = t; i < nbkt; i += 512) sm.bin.lcnt[i] = 0;
        __syncthreads();
        int rk[16];
        #pragma unroll
        for (int i = 0; i < 16; ++i) {
            int e = eb + i * 512 + t;
            rk[i] = -1;
            if (e < n_edges) {
                int r = erow[e];
                int bkt = r >> 7;
                int rank = atomicAdd(&sm.bin.lcnt[bkt], 1);   // < 8192: 13 bits
                rk[i] = (bkt << 20) | ((r & (BK - 1)) << 13) | rank;
            }
        }
        __syncthreads();
        for (int i = t; i < nbkt; i += 512) {
            int c = sm.bin.lcnt[i];
            if (c > 0) sm.bin.goff[i] = atomicAdd(&gcnt[i], c);  // reserve range
        }
        __syncthreads();
        #pragma unroll
        for (int i = 0; i < 16; ++i) {
            int e = eb + i * 512 + t;
            if (e >= n_edges) continue;
            int bkt = rk[i] >> 20, lr = (rk[i] >> 13) & 127, rank = rk[i] & 8191;
            int pos = sm.bin.goff[bkt] + rank;
            if (pos < BCAP)
                binned[(size_t)bkt * BCAP + pos] =
                    make_int2((lr << 17) | ecol[e], __float_as_int(eval_[e]));
        }
        return;
    }

    // ---------------- linear part ----------------
    const int lane = t & 63;
    const int w = t >> 6;
    const int n0 = ((int)blockIdx.x - nbB) * DD;

    #pragma unroll
    for (int rep = 0; rep < 2; ++rep) {
        int i = rep * 512 + t;
        int nd = i >> 4, q = i & 15;
        int node = n0 + nd;
        const float4* src = reinterpret_cast<const float4*>(
            x + (size_t)(node < n_nodes ? node : 0) * DD);
        float4 v = src[q];
        float* d = &sm.lin.tile[nd * 65 + q * 4];
        d[0] = v.x; d[1] = v.y; d[2] = v.z; d[3] = v.w;
    }
    if (t < 64) {          // wave 0: hyperbolic bias hb = proj(expmap0(b))
        float bv = bvec[t];
        float n2 = wsum(bv * bv);
        float n = fmaxf(sqrtf(n2), FEPS);
        float th = tanhf(n);
        float p = th * (bv / n);
        float pn = th * (sqrtf(n2) / n);
        float pn_c = fmaxf(pn, FEPS);
        if (pn_c > MAXN) p *= MAXN / pn_c;
        sm.lin.hb[t] = p;
        float p2 = wsum(p * p);
        if (t == 0) sm.lin.hb[DD] = p2;
    }
    __syncthreads();

    const int jbase = __builtin_amdgcn_readfirstlane(w) * 8;
    float mx[8] = {0.f, 0.f, 0.f, 0.f, 0.f, 0.f, 0.f, 0.f};
    float xn2 = 0.f;
    #pragma unroll
    for (int kk = 0; kk < 4; ++kk) {
        float xv[16];
        #pragma unroll
        for (int ki = 0; ki < 16; ++ki)
            xv[ki] = sm.lin.tile[lane * 65 + kk * 16 + ki];
        #pragma unroll
        for (int ki = 0; ki < 16; ++ki)
            xn2 = fmaf(xv[ki], xv[ki], xn2);
        #pragma unroll
        for (int jj = 0; jj < 8; ++jj) {
            const float* Wr = W + (jbase + jj) * DD + kk * 16;   // uniform -> s_load
            float a = mx[jj];
            #pragma unroll
            for (int ki = 0; ki < 16; ++ki) a = fmaf(Wr[ki], xv[ki], a);
            mx[jj] = a;
        }
    }
    float mx2p = 0.f, mxhp = 0.f;
    #pragma unroll
    for (int jj = 0; jj < 8; ++jj) {
        mx2p = fmaf(mx[jj], mx[jj], mx2p);
        mxhp = fmaf(mx[jj], sm.lin.hb[jbase + jj], mxhp);
    }
    sm.lin.red0[w][lane] = mx2p;
    sm.lin.red1[w][lane] = mxhp;
    __syncthreads();

    if (t < 64) {          // wave 0 ONLY: per-node scalar chain
        float mx2 = 0.f, mxh = 0.f;
        #pragma unroll
        for (int ww = 0; ww < 8; ++ww) {
            mx2 += sm.lin.red0[ww][t];
            mxh += sm.lin.red1[ww][t];
        }
        float xn = fmaxf(sqrtf(xn2), FEPS);      // wave0's own xn2 (lane=node)
        float mxn = fmaxf(sqrtf(mx2), FEPS);
        float th = tanhf((mxn / xn) * artanh_c(xn));
        float sres = (mx2 == 0.f) ? 0.f : th / mxn;
        float rn = (mx2 == 0.f) ? 0.f : th * (sqrtf(mx2) / mxn);
        float rn_c = fmaxf(rn, FEPS);
        float s1 = (rn_c > MAXN) ? sres * (MAXN / rn_c) : sres;
        float x2r = s1 * s1 * mx2;
        float xy = s1 * mxh;
        float y2 = sm.lin.hb[DD];
        float ca = 1.f + 2.f * xy + y2;
        float cb = 1.f - x2r;
        float rden = 1.f / fmaxf(1.f + 2.f * xy + x2r * y2, FEPS);
        float al = ca * s1 * rden;
        float be = cb * rden;
        float h2 = al * al * mx2 + 2.f * al * be * mxh + be * be * y2;
        float hn = fmaxf(sqrtf(h2), FEPS);
        float sh = 1.f;
        if (hn > MAXN) { sh = MAXN / hn; hn = MAXN; }
        float su = sh * (artanh_c(hn) / hn);
        sm.lin.Ab[t] = su * al;
        sm.lin.Bb[t] = su * be;
    }
    __syncthreads();

    // direct fp16 store: thread owns (node=lane, j in [jbase, jbase+8)) = 16 B
    int node = n0 + lane;
    if (node < n_nodes) {
        float A = sm.lin.Ab[lane], B = sm.lin.Bb[lane];
        float u[8];
        #pragma unroll
        for (int jj = 0; jj < 8; ++jj)
            u[jj] = fmaf(A, mx[jj], B * sm.lin.hb[jbase + jj]);
        __half2 p0 = __floats2half2_rn(u[0], u[1]);
        __half2 p1 = __floats2half2_rn(u[2], u[3]);
        __half2 p2 = __floats2half2_rn(u[4], u[5]);
        __half2 p3 = __floats2half2_rn(u[6], u[7]);
        uint4 o;
        o.x = *reinterpret_cast<unsigned int*>(&p0);
        o.y = *reinterpret_cast<unsigned int*>(&p1);
        o.z = *reinterpret_cast<unsigned int*>(&p2);
        o.w = *reinterpret_cast<unsigned int*>(&p3);
        *reinterpret_cast<uint4*>(xth + (size_t)node * DD + jbase) = o;
    }
}

// folded epilogue: o = K(n2, sp2) * relu(s)
__device__ __forceinline__ void agg_epilogue(
    float4 acc, int row, int fl, float* __restrict__ out) {
    float4 s;
    s.x = fminf(acc.x, 1e6f); s.y = fminf(acc.y, 1e6f);
    s.z = fminf(acc.z, 1e6f); s.w = fminf(acc.w, 1e6f);
    float4 rs;
    rs.x = fmaxf(s.x, 0.f); rs.y = fmaxf(s.y, 0.f);
    rs.z = fmaxf(s.z, 0.f); rs.w = fmaxf(s.w, 0.f);
    float n2p = s.x * s.x + s.y * s.y + s.z * s.z + s.w * s.w;
    float sp2p = rs.x * rs.x + rs.y * rs.y + rs.z * rs.z + rs.w * rs.w;
    #pragma unroll
    for (int m = 1; m < 16; m <<= 1) {
        n2p += __shfl_xor(n2p, m);
        sp2p += __shfl_xor(sp2p, m);
    }
    float n = fmaxf(sqrtf(n2p), FEPS);
    float th = tanhf(n);
    float c1 = th / n;
    float pn = th * (sqrtf(n2p) / n);
    float pn_c = fmaxf(pn, FEPS);
    if (pn_c > MAXN) { c1 *= MAXN / pn_c; pn_c = MAXN; }
    float k1 = (artanh_c(pn_c) / pn_c) * c1;
    float u2 = k1 * k1 * sp2p;
    float un = fmaxf(sqrtf(u2), FEPS);
    float t2 = tanhf(un);
    float k2 = (t2 / un) * k1;
    float on = t2 * (sqrtf(u2) / un);
    float on_c = fmaxf(on, FEPS);
    if (on_c > MAXN) k2 *= MAXN / on_c;
    float4 o;
    o.x = k2 * rs.x; o.y = k2 * rs.y; o.z = k2 * rs.z; o.w = k2 * rs.w;
    reinterpret_cast<float4*>(out)[(size_t)row * 16 + fl] = o;
}

// block = bucket (128 rows), 512 threads = 32 groups x 16 lanes.
// In-LDS counting sort by row, then register accumulation, 8-deep gathers
// (mean degree 8 -> one fully-pipelined iteration covers most rows).
__global__ __launch_bounds__(512) void kagg2(
    const int* __restrict__ gcnt, const int2* __restrict__ binned,
    const __half* __restrict__ xth, float* __restrict__ out, int n_nodes) {
    __shared__ int hist[BK], offs[BK], cur[BK];
    __shared__ int2 srt[BCAP];
    const int t = threadIdx.x;
    const int b = blockIdx.x;
    for (int i = t; i < BK; i += 512) hist[i] = 0;
    __syncthreads();
    const int nrec = min(gcnt[b], BCAP);
    const int2* rec = binned + (size_t)b * BCAP;
    int2 rc[BCAP / 512];
    #pragma unroll
    for (int i = 0; i < BCAP / 512; ++i) {
        int j = i * 512 + t;
        if (j < nrec) {
            rc[i] = rec[j];
            atomicAdd(&hist[rc[i].x >> 17], 1);
        }
    }
    __syncthreads();
    if (t < 64) {                         // scan 128 counters with one wave
        int v = hist[t];
        int s = wave_incl_scan(v);
        offs[t] = s - v;
    }
    __syncthreads();
    if (t < 64) {
        int c = offs[63] + hist[63];
        int v = hist[64 + t];
        int s = wave_incl_scan(v);
        offs[64 + t] = c + s - v;
    }
    __syncthreads();
    for (int i = t; i < BK; i += 512) cur[i] = offs[i];
    __syncthreads();
    #pragma unroll
    for (int i = 0; i < BCAP / 512; ++i) {
        int j = i * 512 + t;
        if (j < nrec) {
            int lr = rc[i].x >> 17;
            int p = atomicAdd(&cur[lr], 1);
            srt[p] = make_int2(rc[i].x & 0x1FFFF, rc[i].y);
        }
    }
    __syncthreads();

    const int g = t >> 4, fl = t & 15;    // 32 groups x 16 lanes
    #pragma unroll
    for (int it = 0; it < BK / 32; ++it) {
        int lr = it * 32 + g;
        int row = b * BK + lr;
        if (row >= n_nodes) continue;
        int beg = offs[lr], end = beg + hist[lr];
        float4 acc = make_float4(0.f, 0.f, 0.f, 0.f);
        int j = beg;
        for (; j + 7 < end; j += 8) {     // 8-deep gather pipelining
            int2 e[8];
            float2 r[8];
            #pragma unroll
            for (int q = 0; q < 8; ++q) e[q] = srt[j + q];
            #pragma unroll
            for (int q = 0; q < 8; ++q)
                r[q] = *reinterpret_cast<const float2*>(
                    xth + (size_t)e[q].x * DD + fl * 4);
            #pragma unroll
            for (int q = 0; q < 8; ++q) {
                float wq = __int_as_float(e[q].y);
                float2 lo = __half22float2(*reinterpret_cast<__half2*>(&r[q].x));
                float2 hi = __half22float2(*reinterpret_cast<__half2*>(&r[q].y));
                acc.x = fmaf(wq, lo.x, acc.x); acc.y = fmaf(wq, lo.y, acc.y);
                acc.z = fmaf(wq, hi.x, acc.z); acc.w = fmaf(wq, hi.y, acc.w);
            }
        }
        for (; j + 3 < end; j += 4) {     // 4-deep
            int2 e[4];
            float2 r[4];
            #pragma unroll
            for (int q = 0; q < 4; ++q) e[q] = srt[j + q];
            #pragma unroll
            for (int q = 0; q < 4; ++q)
                r[q] = *reinterpret_cast<const float2*>(
                    xth + (size_t)e[q].x * DD + fl * 4);
            #pragma unroll
            for (int q = 0; q < 4; ++q) {
                float wq = __int_as_float(e[q].y);
                float2 lo = __half22float2(*reinterpret_cast<__half2*>(&r[q].x));
                float2 hi = __half22float2(*reinterpret_cast<__half2*>(&r[q].y));
                acc.x = fmaf(wq, lo.x, acc.x); acc.y = fmaf(wq, lo.y, acc.y);
                acc.z = fmaf(wq, hi.x, acc.z); acc.w = fmaf(wq, hi.y, acc.w);
            }
        }
        for (; j < end; ++j) {
            int2 e = srt[j];
            float2 r0 = *reinterpret_cast<const float2*>(
                xth + (size_t)e.x * DD + fl * 4);
            float w0 = __int_as_float(e.y);
            float2 lo = __half22float2(*reinterpret_cast<__half2*>(&r0.x));
            float2 hi = __half22float2(*reinterpret_cast<__half2*>(&r0.y));
            acc.x = fmaf(w0, lo.x, acc.x); acc.y = fmaf(w0, lo.y, acc.y);
            acc.z = fmaf(w0, hi.x, acc.z); acc.w = fmaf(w0, hi.y, acc.w);
        }
        agg_epilogue(acc, row, fl, out);
    }
}

extern "C" void kernel_launch(void* const* d_in, const int* in_sizes, int n_in,
                              void* d_out, int out_size, void* d_ws, size_t ws_size,
                              hipStream_t stream) {
    const float* x     = (const float*)d_in[0];
    const float* W     = (const float*)d_in[1];
    const float* b     = (const float*)d_in[2];
    const int*   erow  = (const int*)d_in[3];
    const int*   ecol  = (const int*)d_in[4];
    const float* eval_ = (const float*)d_in[5];
    const int n_nodes = in_sizes[0] / DD;   // 100000
    const int n_edges = in_sizes[3];        // 800000
    float* out = (float*)d_out;

    const int NBKT = (n_nodes + BK - 1) / BK;           // 782 (<= NBKT_MAX)

    // ws layout: binned | xth | gcnt   (~25.6 MB total)
    int2*   binned = (int2*)d_ws;                       // NBKT*BCAP int2
    __half* xth    = (__half*)(binned + (size_t)NBKT * BCAP);
    int*    gcnt   = (int*)(xth + (size_t)n_nodes * DD);

    const int nbB = (n_edges + CHUNK - 1) / CHUNK;      // 98
    const int nbL = (n_nodes + DD - 1) / DD;            // 1563

    hipMemsetAsync(gcnt, 0, NBKT_MAX * sizeof(int), stream);
    kfused<<<nbB + nbL, 512, 0, stream>>>(x, W, b, xth, erow, ecol, eval_,
                                          gcnt, binned, NBKT, n_edges, n_nodes, nbB);
    kagg2<<<NBKT, 512, 0, stream>>>(gcnt, binned, xth, out, n_nodes);
}